// Round 3
// baseline (298.058 us; speedup 1.0000x reference)
//
#include <hip/hip_runtime.h>
#include <hip/hip_bf16.h>
#include <math.h>

typedef __bf16 bf16_8 __attribute__((ext_vector_type(8)));
typedef __bf16 bf16_4 __attribute__((ext_vector_type(4)));
typedef float f32x4 __attribute__((ext_vector_type(4)));

#define NDIM 1024

__device__ static inline void async_copy16(const void* g, void* l) {
  __builtin_amdgcn_global_load_lds(
      (__attribute__((address_space(1))) void*)g,
      (__attribute__((address_space(3))) void*)l, 16, 0, 0);
}

// ======================= FAST PATH (needs 66 MB workspace) =======================
// DCT symmetry fold: C[k][1023-j] = (-1)^k * C[k][j]:
//   out[2k'][n]   = sum_{j<512} C[2k'][j]   * (x[j][n] + x[1023-j][n])
//   out[2k'+1][n] = sum_{j<512} C[2k'+1][j] * (x[j][n] - x[1023-j][n])
// -> two 512x1024x512 GEMMs. Operands pre-blocked as 16 KB swizzled "LDS images"
// ([128 rows][64 k] bf16, 16B slot s stored at position s^(r&7)).
// A (1 MB total) stays L2-resident: the GEMM reads A fragments directly from
// global; only the streamed x-derived U/V images go through LDS via DMA.

// Ae (sel=0) / Ao (sel=1): half-matrix [512 m'][512 j], blocked+swizzled.
__global__ void gen_dct_fold(__bf16* __restrict__ A) {
  int idx = blockIdx.x * blockDim.x + threadIdx.x;  // 0..65535
  int sel = idx >> 15;
  int rem = idx & 32767;
  int mp = rem >> 6;    // m' 0..511 (row within half-matrix)
  int slot = rem & 63;  // 16B slot within 512-wide j row
  int kt = slot >> 3, s = slot & 7;
  int k = 2 * mp + sel;  // actual DCT row
  int r = mp & 127, mtp = mp >> 7;
  float sc = (k == 0) ? 0.03125f : 0.04419417382415922f;
  int jb = kt * 64 + s * 8;
  bf16_8 v;
#pragma unroll
  for (int q = 0; q < 8; q++) {
    int j = jb + q;
    int t = (k * (2 * j + 1)) & 4095;               // exact phase mod 2*pi
    float ang = (float)t * 1.5339807878856412e-3f;  // pi/2048
    v[q] = (__bf16)(sc * cosf(ang));
  }
  *(bf16_8*)(A + (((size_t)(sel * 32 + mtp * 8 + kt)) << 13) + r * 64 +
             ((s ^ (r & 7)) << 3)) = v;
}

// x[b][j][n] f32 -> folded U/V blocked bf16 images.
// Image (b, sel, nt, kt) = [n=128 rows][j'=64] swizzled, at
//   B + ((b*2+sel)*64 + nt*8 + kt) * 8192.
#define TFP 132  // padded bf16 row stride: spreads transpose-read banks, keeps 8B align
__global__ __launch_bounds__(256) void fold_cvt(const float* __restrict__ x,
                                                __bf16* __restrict__ B) {
  __shared__ __bf16 Tu[64 * TFP];  // [j_local][n] bf16
  __shared__ __bf16 Tv[64 * TFP];
  const int t = threadIdx.x;
  const int kt = blockIdx.x, nt = blockIdx.y, b = blockIdx.z;
  const float* xb = x + (size_t)b * (NDIM * NDIM) + nt * 128;
  const int kr = t >> 5;        // 0..7
  const int c4 = (t & 31) * 4;  // float col (16B chunk)
  const int jb = kt * 64;         // top rows j = jb + k
  const int mb = 1023 - kt * 64;  // mirror rows = mb - k
#pragma unroll
  for (int u = 0; u < 8; u++) {
    int k = u * 8 + kr;
    f32x4 a = *(const f32x4*)(xb + (size_t)(jb + k) * NDIM + c4);
    f32x4 m = *(const f32x4*)(xb + (size_t)(mb - k) * NDIM + c4);
    f32x4 su = a + m, dv = a - m;
    bf16_4 wu, wv;
#pragma unroll
    for (int i = 0; i < 4; i++) {
      wu[i] = (__bf16)su[i];
      wv[i] = (__bf16)dv[i];
    }
    *(bf16_4*)(&Tu[k * TFP + c4]) = wu;  // banks: 2-way -> free
    *(bf16_4*)(&Tv[k * TFP + c4]) = wv;
  }
  __syncthreads();
  __bf16* outU = B + (((size_t)(b * 2 + 0) * 64 + nt * 8 + kt) << 13);
  __bf16* outV = B + (((size_t)(b * 2 + 1) * 64 + nt * 8 + kt) << 13);
#pragma unroll
  for (int u = 0; u < 4; u++) {
    int c = t * 4 + u;  // 16B output chunk; thread owns 64 contiguous bytes
    int r = c >> 3, sp = c & 7;
    int s = sp ^ (r & 7);  // data slot stored at position sp
    bf16_8 vU, vV;
#pragma unroll
    for (int q = 0; q < 8; q++) {  // transpose read; TFP pad spreads banks
      vU[q] = Tu[(s * 8 + q) * TFP + r];
      vV[q] = Tv[(s * 8 + q) * TFP + r];
    }
    *(bf16_8*)(outU + c * 8) = vU;
    *(bf16_8*)(outV + c * 8) = vV;
  }
}

// 128x128 tile, K=512 (8 steps of BK=64). B (U/V) double-buffered in 32 KB LDS
// via DMA; A fragments read directly from the L2-resident blocked image.
// 4 blocks/CU (vs 2 at 64 KB LDS) -> barrier drains covered by co-resident waves.
__global__ __launch_bounds__(256, 4) void dct_gemm4(
    const __bf16* __restrict__ A, const __bf16* __restrict__ B,
    float* __restrict__ out) {
  __shared__ __align__(1024) __bf16 Bs[2][128 * 64];  // 2 x 16 KB
  const int t = threadIdx.x;
  const int w = t >> 6, lane = t & 63;
  const int nt = blockIdx.x, b = blockIdx.z;
  const int sel = blockIdx.y & 1, mtp = blockIdx.y >> 1;

  const __bf16* bg =
      B + (((size_t)(b * 2 + sel) * 64 + nt * 8) << 13) + w * 2048 + lane * 8;

  const int r16 = lane & 15;
  const int g8 = (lane >> 4) << 3;
  const int wm = (w & 1) << 6, wn = (w >> 1) << 6;
  const int xr = (r16 & 7) << 3;    // swizzle term (element units)
  const int kof0 = g8 ^ xr;         // k-half 0
  const int kof1 = (32 + g8) ^ xr;  // k-half 1

  // A fragment base: row (wm + i*16 + r16) of image (sel*32 + mtp*8 + kt)
  const __bf16* agf =
      A + (((size_t)(sel * 32 + mtp * 8)) << 13) + (size_t)(wm + r16) * 64;

  // prologue: stage B tile 0
#pragma unroll
  for (int i = 0; i < 4; i++)
    async_copy16(bg + i * 512, &Bs[0][w * 2048 + i * 512]);
  __syncthreads();  // tile 0 resident

  f32x4 acc[4][4] = {};

  for (int kt = 0; kt < 8; kt++) {
    const int cur = kt & 1;
    if (kt < 7) {  // prefetch next B tile into the other buffer
      const __bf16* bn = bg + (size_t)(kt + 1) * 8192;
#pragma unroll
      for (int i = 0; i < 4; i++)
        async_copy16(bn + i * 512, &Bs[cur ^ 1][w * 2048 + i * 512]);
    }
    const __bf16* as = agf + (size_t)kt * 8192;
    const __bf16* bs = &Bs[cur][0];
#pragma unroll
    for (int h = 0; h < 2; h++) {
      const int kof = h ? kof1 : kof0;
      bf16_8 af[4], bfr[4];
#pragma unroll
      for (int i = 0; i < 4; i++)  // global (L2-hot) A fragment loads
        af[i] = *(const bf16_8*)(as + i * 1024 + kof);
#pragma unroll
      for (int j = 0; j < 4; j++)
        bfr[j] = *(const bf16_8*)(bs + (wn + j * 16 + r16) * 64 + kof);
#pragma unroll
      for (int i = 0; i < 4; i++)
#pragma unroll
        for (int j = 0; j < 4; j++)
          acc[i][j] = __builtin_amdgcn_mfma_f32_16x16x32_bf16(af[i], bfr[j],
                                                              acc[i][j], 0, 0, 0);
    }
    __syncthreads();  // next B tile staged + cur reads done block-wide
  }

  // epilogue: C/D layout col = lane&15, row_half = (lane>>4)*4 + reg;
  // physical out row = 2*row_half_global + sel (even/odd interleave).
  float* ob = out + (size_t)b * (NDIM * NDIM);
  const int rbase = (lane >> 4) << 2;
  const int cofs = lane & 15;
  const int n0 = nt * 128;
#pragma unroll
  for (int i = 0; i < 4; i++)
#pragma unroll
    for (int rr = 0; rr < 4; rr++) {
      int rh = mtp * 128 + wm + i * 16 + rbase + rr;
      int row = rh * 2 + sel;
#pragma unroll
      for (int j = 0; j < 4; j++) {
        int col = n0 + wn + j * 16 + cofs;
        ob[(size_t)row * NDIM + col] = acc[i][j][rr];
      }
    }
}

// ======================= FALLBACK PATH (small workspace) =======================
#define BM 128
#define BN 128
#define BK 32
#define BSTRIDE 40

__global__ void gen_dct_mat(__bf16* __restrict__ C) {
  int idx = blockIdx.x * blockDim.x + threadIdx.x;
  int k = idx >> 10;
  int j = idx & 1023;
  int t = (k * (2 * j + 1)) & 4095;
  float ang = (float)t * 1.5339807878856412e-3f;
  float s = (k == 0) ? 0.03125f : 0.04419417382415922f;
  C[idx] = (__bf16)(s * cosf(ang));
}

__global__ __launch_bounds__(256) void dct_gemm(
    const float* __restrict__ x, const __bf16* __restrict__ A,
    float* __restrict__ out) {
  __shared__ __align__(64) __bf16 Asm[BM * BK];
  __shared__ __align__(64) __bf16 Bsm[BN * BSTRIDE];

  const int t = threadIdx.x;
  const int wave = t >> 6;
  const int lane = t & 63;
  const int bb = blockIdx.z;
  const int m0 = blockIdx.y * BM;
  const int n0 = blockIdx.x * BN;

  const __bf16* Ag0 =
      A + (size_t)(m0 + wave * 16 + (lane >> 2)) * NDIM + ((lane & 3) * 8);
  const __bf16* Ag1 = Ag0 + (size_t)64 * NDIM;
  __bf16* Al0 = Asm + (wave * 16) * BK;
  __bf16* Al1 = Asm + (64 + wave * 16) * BK;

  const int bc = t & 127;
  const int bjg = t >> 7;
  const float* xs =
      x + (size_t)bb * (NDIM * NDIM) + (size_t)(bjg * 16) * NDIM + (n0 + bc);
  bf16_8* bs0 = (bf16_8*)(Bsm + bc * BSTRIDE + bjg * 16);
  bf16_8* bs1 = (bf16_8*)(Bsm + bc * BSTRIDE + bjg * 16 + 8);

  const int row16 = lane & 15;
  const int kq8 = (lane >> 4) * 8;
  const int wm = (wave & 1) * 64;
  const int wn = (wave >> 1) * 64;

  f32x4 acc[4][4] = {};

  for (int k0 = 0; k0 < NDIM; k0 += BK) {
    __syncthreads();
    async_copy16(Ag0 + k0, Al0);
    async_copy16(Ag1 + k0, Al1);

    const float* xp = xs + (size_t)k0 * NDIM;
    bf16_8 v0, v1;
#pragma unroll
    for (int q = 0; q < 8; q++) {
      v0[q] = (__bf16)xp[(size_t)q * NDIM];
      v1[q] = (__bf16)xp[(size_t)(q + 8) * NDIM];
    }
    *bs0 = v0;
    *bs1 = v1;
    __syncthreads();

    bf16_8 af[4], bfr[4];
#pragma unroll
    for (int i = 0; i < 4; i++)
      af[i] = *(const bf16_8*)(Asm + (wm + i * 16 + row16) * BK + kq8);
#pragma unroll
    for (int j = 0; j < 4; j++)
      bfr[j] = *(const bf16_8*)(Bsm + (wn + j * 16 + row16) * BSTRIDE + kq8);
#pragma unroll
    for (int i = 0; i < 4; i++)
#pragma unroll
      for (int j = 0; j < 4; j++)
        acc[i][j] = __builtin_amdgcn_mfma_f32_16x16x32_bf16(af[i], bfr[j],
                                                            acc[i][j], 0, 0, 0);
  }

  float* ob = out + (size_t)bb * (NDIM * NDIM);
  const int rbase = (lane >> 4) * 4;
  const int cofs = lane & 15;
#pragma unroll
  for (int i = 0; i < 4; i++) {
#pragma unroll
    for (int r = 0; r < 4; r++) {
      int row = m0 + wm + i * 16 + rbase + r;
#pragma unroll
      for (int j = 0; j < 4; j++) {
        int col = n0 + wn + j * 16 + cofs;
        ob[(size_t)row * NDIM + col] = acc[i][j][r];
      }
    }
  }
}

extern "C" void kernel_launch(void* const* d_in, const int* in_sizes, int n_in,
                              void* d_out, int out_size, void* d_ws,
                              size_t ws_size, hipStream_t stream) {
  const float* x = (const float*)d_in[0];
  float* out = (float*)d_out;

  const size_t need = (size_t)66 * 1024 * 1024;  // 2 MB A + 64 MB folded U/V
  if (ws_size >= need) {
    __bf16* Ab = (__bf16*)d_ws;                       // 2*512*512 bf16 = 1 MB
    __bf16* Bb = (__bf16*)((char*)d_ws + (size_t)2 * 1024 * 1024);  // 64 MB
    gen_dct_fold<<<dim3(256), dim3(256), 0, stream>>>(Ab);
    fold_cvt<<<dim3(8, 8, 32), dim3(256), 0, stream>>>(x, Bb);
    dct_gemm4<<<dim3(8, 8, 32), dim3(256), 0, stream>>>(Ab, Bb, out);
  } else {
    __bf16* Cmat = (__bf16*)d_ws;  // 2 MB
    gen_dct_mat<<<dim3((NDIM * NDIM) / 256), dim3(256), 0, stream>>>(Cmat);
    dct_gemm<<<dim3(NDIM / BN, NDIM / BM, 32), dim3(256), 0, stream>>>(x, Cmat,
                                                                       out);
  }
}

// Round 5
// 272.908 us; speedup vs baseline: 1.0922x; 1.0922x over previous
//
#include <hip/hip_runtime.h>
#include <hip/hip_bf16.h>
#include <math.h>

typedef __bf16 bf16_8 __attribute__((ext_vector_type(8)));
typedef __bf16 bf16_4 __attribute__((ext_vector_type(4)));
typedef float f32x4 __attribute__((ext_vector_type(4)));

#define NDIM 1024

__device__ static inline void async_copy16(const void* g, void* l) {
  __builtin_amdgcn_global_load_lds(
      (__attribute__((address_space(1))) void*)g,
      (__attribute__((address_space(3))) void*)l, 16, 0, 0);
}

// ======================= FAST PATH (needs 66 MB workspace) =======================
// DCT symmetry fold: C[k][1023-j] = (-1)^k * C[k][j]:
//   out[2k'][n]   = sum_{j<512} C[2k'][j]   * (x[j][n] + x[1023-j][n])
//   out[2k'+1][n] = sum_{j<512} C[2k'+1][j] * (x[j][n] - x[1023-j][n])
// -> two 512x1024x512 GEMMs. Operands pre-blocked as 16 KB swizzled "LDS images"
// ([128 rows][64 k] bf16, 16B slot s stored at position s^(r&7)).
// A (1 MB) is L2-resident and read straight into registers; only the streamed
// U/V images go through LDS via DMA. Issue ORDER inside the K-loop matters:
// A-loads FIRST, then prefetch DMAs -> compiler's pre-MFMA wait is vmcnt(4),
// leaving the DMAs in flight across the MFMA body (gemm4 had them reversed,
// which drained the prefetch before compute every step: 78.6 us).

// Ae (sel=0) / Ao (sel=1): half-matrix [512 m'][512 j], blocked+swizzled.
__global__ void gen_dct_fold(__bf16* __restrict__ A) {
  int idx = blockIdx.x * blockDim.x + threadIdx.x;  // 0..65535
  int sel = idx >> 15;
  int rem = idx & 32767;
  int mp = rem >> 6;    // m' 0..511 (row within half-matrix)
  int slot = rem & 63;  // 16B slot within 512-wide j row
  int kt = slot >> 3, s = slot & 7;
  int k = 2 * mp + sel;  // actual DCT row
  int r = mp & 127, mtp = mp >> 7;
  float sc = (k == 0) ? 0.03125f : 0.04419417382415922f;
  int jb = kt * 64 + s * 8;
  bf16_8 v;
#pragma unroll
  for (int q = 0; q < 8; q++) {
    int j = jb + q;
    int t = (k * (2 * j + 1)) & 4095;               // exact phase mod 2*pi
    float ang = (float)t * 1.5339807878856412e-3f;  // pi/2048
    v[q] = (__bf16)(sc * cosf(ang));
  }
  *(bf16_8*)(A + (((size_t)(sel * 32 + mtp * 8 + kt)) << 13) + r * 64 +
             ((s ^ (r & 7)) << 3)) = v;
}

// x[b][j][n] f32 -> folded U/V blocked bf16 images.
// Image (b, sel, nt, kt) = [n=128 rows][j'=64] swizzled, at
//   B + ((b*2+sel)*64 + nt*8 + kt) * 8192.
#define TFP 132  // padded bf16 row stride: spreads transpose-read banks, keeps 8B align
__global__ __launch_bounds__(256) void fold_cvt(const float* __restrict__ x,
                                                __bf16* __restrict__ B) {
  __shared__ __bf16 Tu[64 * TFP];  // [j_local][n] bf16
  __shared__ __bf16 Tv[64 * TFP];
  const int t = threadIdx.x;
  const int kt = blockIdx.x, nt = blockIdx.y, b = blockIdx.z;
  const float* xb = x + (size_t)b * (NDIM * NDIM) + nt * 128;
  const int kr = t >> 5;        // 0..7
  const int c4 = (t & 31) * 4;  // float col (16B chunk)
  const int jb = kt * 64;         // top rows j = jb + k
  const int mb = 1023 - kt * 64;  // mirror rows = mb - k
#pragma unroll
  for (int u = 0; u < 8; u++) {
    int k = u * 8 + kr;
    f32x4 a = *(const f32x4*)(xb + (size_t)(jb + k) * NDIM + c4);
    f32x4 m = *(const f32x4*)(xb + (size_t)(mb - k) * NDIM + c4);
    f32x4 su = a + m, dv = a - m;
    bf16_4 wu, wv;
#pragma unroll
    for (int i = 0; i < 4; i++) {
      wu[i] = (__bf16)su[i];
      wv[i] = (__bf16)dv[i];
    }
    *(bf16_4*)(&Tu[k * TFP + c4]) = wu;  // banks: 2-way -> free
    *(bf16_4*)(&Tv[k * TFP + c4]) = wv;
  }
  __syncthreads();
  __bf16* outU = B + (((size_t)(b * 2 + 0) * 64 + nt * 8 + kt) << 13);
  __bf16* outV = B + (((size_t)(b * 2 + 1) * 64 + nt * 8 + kt) << 13);
#pragma unroll
  for (int u = 0; u < 4; u++) {
    int c = t * 4 + u;  // 16B output chunk; thread owns 64 contiguous bytes
    int r = c >> 3, sp = c & 7;
    int s = sp ^ (r & 7);  // data slot stored at position sp
    bf16_8 vU, vV;
#pragma unroll
    for (int q = 0; q < 8; q++) {  // transpose read; TFP pad spreads banks
      vU[q] = Tu[(s * 8 + q) * TFP + r];
      vV[q] = Tv[(s * 8 + q) * TFP + r];
    }
    *(bf16_8*)(outU + c * 8) = vU;
    *(bf16_8*)(outV + c * 8) = vV;
  }
}

// 128x128 tile, K=512 (8 steps of BK=64). B (U/V) double-buffered in 32 KB LDS
// via DMA; A fragments loaded to REGISTERS from the L2-resident blocked image,
// issued BEFORE each step's prefetch DMAs (vmcnt-decoupled, see header comment).
__global__ __launch_bounds__(256, 3) void dct_gemm5(
    const __bf16* __restrict__ A, const __bf16* __restrict__ B,
    float* __restrict__ out) {
  __shared__ __align__(1024) __bf16 Bs[2][128 * 64];  // 2 x 16 KB
  const int t = threadIdx.x;
  const int w = t >> 6, lane = t & 63;
  const int nt = blockIdx.x, b = blockIdx.z;
  const int sel = blockIdx.y & 1, mtp = blockIdx.y >> 1;

  const __bf16* bg =
      B + (((size_t)(b * 2 + sel) * 64 + nt * 8) << 13) + w * 2048 + lane * 8;

  const int r16 = lane & 15;
  const int g8 = (lane >> 4) << 3;
  const int wm = (w & 1) << 6, wn = (w >> 1) << 6;
  const int xr = (r16 & 7) << 3;    // swizzle term (element units)
  const int kof0 = g8 ^ xr;         // k-half 0
  const int kof1 = (32 + g8) ^ xr;  // k-half 1

  // A fragment base: row (wm + i*16 + r16) of image (sel*32 + mtp*8 + kt)
  const __bf16* agf =
      A + (((size_t)(sel * 32 + mtp * 8)) << 13) + (size_t)(wm + r16) * 64;

  // prologue: stage B tile 0
#pragma unroll
  for (int i = 0; i < 4; i++)
    async_copy16(bg + i * 512, &Bs[0][w * 2048 + i * 512]);
  __syncthreads();  // tile 0 resident

  f32x4 acc[4][4] = {};

#pragma unroll
  for (int kt = 0; kt < 8; kt++) {
    const int cur = kt & 1;
    const __bf16* as = agf + (size_t)kt * 8192;

    // (1) A-fragment loads FIRST (oldest in vmcnt queue)
    bf16_8 a0[4], a1[4];
#pragma unroll
    for (int i = 0; i < 4; i++) {
      a0[i] = *(const bf16_8*)(as + i * 1024 + kof0);
      a1[i] = *(const bf16_8*)(as + i * 1024 + kof1);
    }
    __builtin_amdgcn_sched_barrier(0);

    // (2) then the next-tile prefetch DMAs (youngest; stay in flight)
    if (kt < 7) {
      const __bf16* bn = bg + (size_t)(kt + 1) * 8192;
#pragma unroll
      for (int i = 0; i < 4; i++)
        async_copy16(bn + i * 512, &Bs[cur ^ 1][w * 2048 + i * 512]);
    }
    __builtin_amdgcn_sched_barrier(0);

    // (3) compute: compiler waits vmcnt(4) (A done, DMAs in flight) + lgkmcnt
    const __bf16* bs = &Bs[cur][0];
#pragma unroll
    for (int h = 0; h < 2; h++) {
      const int kof = h ? kof1 : kof0;
      bf16_8 bfr[4];
#pragma unroll
      for (int j = 0; j < 4; j++)
        bfr[j] = *(const bf16_8*)(bs + (wn + j * 16 + r16) * 64 + kof);
#pragma unroll
      for (int i = 0; i < 4; i++)
#pragma unroll
        for (int j = 0; j < 4; j++)
          acc[i][j] = __builtin_amdgcn_mfma_f32_16x16x32_bf16(
              h ? a1[i] : a0[i], bfr[j], acc[i][j], 0, 0, 0);
    }
    __syncthreads();  // drains DMAs (next tile resident) + cur reads done
  }

  // epilogue: C/D layout col = lane&15, row_half = (lane>>4)*4 + reg;
  // physical out row = 2*row_half_global + sel (even/odd interleave).
  float* ob = out + (size_t)b * (NDIM * NDIM);
  const int rbase = (lane >> 4) << 2;
  const int cofs = lane & 15;
  const int n0 = nt * 128;
#pragma unroll
  for (int i = 0; i < 4; i++)
#pragma unroll
    for (int rr = 0; rr < 4; rr++) {
      int rh = mtp * 128 + wm + i * 16 + rbase + rr;
      int row = rh * 2 + sel;
#pragma unroll
      for (int j = 0; j < 4; j++) {
        int col = n0 + wn + j * 16 + cofs;
        ob[(size_t)row * NDIM + col] = acc[i][j][rr];
      }
    }
}

// ======================= FALLBACK PATH (small workspace) =======================
#define BM 128
#define BN 128
#define BK 32
#define BSTRIDE 40

__global__ void gen_dct_mat(__bf16* __restrict__ C) {
  int idx = blockIdx.x * blockDim.x + threadIdx.x;
  int k = idx >> 10;
  int j = idx & 1023;
  int t = (k * (2 * j + 1)) & 4095;
  float ang = (float)t * 1.5339807878856412e-3f;
  float s = (k == 0) ? 0.03125f : 0.04419417382415922f;
  C[idx] = (__bf16)(s * cosf(ang));
}

__global__ __launch_bounds__(256) void dct_gemm(
    const float* __restrict__ x, const __bf16* __restrict__ A,
    float* __restrict__ out) {
  __shared__ __align__(64) __bf16 Asm[BM * BK];
  __shared__ __align__(64) __bf16 Bsm[BN * BSTRIDE];

  const int t = threadIdx.x;
  const int wave = t >> 6;
  const int lane = t & 63;
  const int bb = blockIdx.z;
  const int m0 = blockIdx.y * BM;
  const int n0 = blockIdx.x * BN;

  const __bf16* Ag0 =
      A + (size_t)(m0 + wave * 16 + (lane >> 2)) * NDIM + ((lane & 3) * 8);
  const __bf16* Ag1 = Ag0 + (size_t)64 * NDIM;
  __bf16* Al0 = Asm + (wave * 16) * BK;
  __bf16* Al1 = Asm + (64 + wave * 16) * BK;

  const int bc = t & 127;
  const int bjg = t >> 7;
  const float* xs =
      x + (size_t)bb * (NDIM * NDIM) + (size_t)(bjg * 16) * NDIM + (n0 + bc);
  bf16_8* bs0 = (bf16_8*)(Bsm + bc * BSTRIDE + bjg * 16);
  bf16_8* bs1 = (bf16_8*)(Bsm + bc * BSTRIDE + bjg * 16 + 8);

  const int row16 = lane & 15;
  const int kq8 = (lane >> 4) * 8;
  const int wm = (wave & 1) * 64;
  const int wn = (wave >> 1) * 64;

  f32x4 acc[4][4] = {};

  for (int k0 = 0; k0 < NDIM; k0 += BK) {
    __syncthreads();
    async_copy16(Ag0 + k0, Al0);
    async_copy16(Ag1 + k0, Al1);

    const float* xp = xs + (size_t)k0 * NDIM;
    bf16_8 v0, v1;
#pragma unroll
    for (int q = 0; q < 8; q++) {
      v0[q] = (__bf16)xp[(size_t)q * NDIM];
      v1[q] = (__bf16)xp[(size_t)(q + 8) * NDIM];
    }
    *bs0 = v0;
    *bs1 = v1;
    __syncthreads();

    bf16_8 af[4], bfr[4];
#pragma unroll
    for (int i = 0; i < 4; i++)
      af[i] = *(const bf16_8*)(Asm + (wm + i * 16 + row16) * BK + kq8);
#pragma unroll
    for (int j = 0; j < 4; j++)
      bfr[j] = *(const bf16_8*)(Bsm + (wn + j * 16 + row16) * BSTRIDE + kq8);
#pragma unroll
    for (int i = 0; i < 4; i++)
#pragma unroll
      for (int j = 0; j < 4; j++)
        acc[i][j] = __builtin_amdgcn_mfma_f32_16x16x32_bf16(af[i], bfr[j],
                                                            acc[i][j], 0, 0, 0);
  }

  float* ob = out + (size_t)bb * (NDIM * NDIM);
  const int rbase = (lane >> 4) * 4;
  const int cofs = lane & 15;
#pragma unroll
  for (int i = 0; i < 4; i++) {
#pragma unroll
    for (int r = 0; r < 4; r++) {
      int row = m0 + wm + i * 16 + rbase + r;
#pragma unroll
      for (int j = 0; j < 4; j++) {
        int col = n0 + wn + j * 16 + cofs;
        ob[(size_t)row * NDIM + col] = acc[i][j][r];
      }
    }
  }
}

extern "C" void kernel_launch(void* const* d_in, const int* in_sizes, int n_in,
                              void* d_out, int out_size, void* d_ws,
                              size_t ws_size, hipStream_t stream) {
  const float* x = (const float*)d_in[0];
  float* out = (float*)d_out;

  const size_t need = (size_t)66 * 1024 * 1024;  // 2 MB A + 64 MB folded U/V
  if (ws_size >= need) {
    __bf16* Ab = (__bf16*)d_ws;                       // 2*512*512 bf16 = 1 MB
    __bf16* Bb = (__bf16*)((char*)d_ws + (size_t)2 * 1024 * 1024);  // 64 MB
    gen_dct_fold<<<dim3(256), dim3(256), 0, stream>>>(Ab);
    fold_cvt<<<dim3(8, 8, 32), dim3(256), 0, stream>>>(x, Bb);
    dct_gemm5<<<dim3(8, 8, 32), dim3(256), 0, stream>>>(Ab, Bb, out);
  } else {
    __bf16* Cmat = (__bf16*)d_ws;  // 2 MB
    gen_dct_mat<<<dim3((NDIM * NDIM) / 256), dim3(256), 0, stream>>>(Cmat);
    dct_gemm<<<dim3(NDIM / BN, NDIM / BM, 32), dim3(256), 0, stream>>>(x, Cmat,
                                                                       out);
  }
}

// Round 6
// 272.468 us; speedup vs baseline: 1.0939x; 1.0016x over previous
//
#include <hip/hip_runtime.h>
#include <hip/hip_bf16.h>
#include <math.h>

typedef __bf16 bf16_8 __attribute__((ext_vector_type(8)));
typedef __bf16 bf16_4 __attribute__((ext_vector_type(4)));
typedef float f32x4 __attribute__((ext_vector_type(4)));

#define NDIM 1024

__device__ static inline void async_copy16(const void* g, void* l) {
  __builtin_amdgcn_global_load_lds(
      (__attribute__((address_space(1))) void*)g,
      (__attribute__((address_space(3))) void*)l, 16, 0, 0);
}

// ======================= FAST PATH (needs 66 MB workspace) =======================
// DCT symmetry fold: C[k][1023-j] = (-1)^k * C[k][j]:
//   out[2k'][n]   = sum_{j<512} C[2k'][j]   * (x[j][n] + x[1023-j][n])
//   out[2k'+1][n] = sum_{j<512} C[2k'+1][j] * (x[j][n] - x[1023-j][n])
// -> two 512x1024x512 GEMMs. Operands pre-blocked as 16 KB swizzled "LDS images"
// ([128 rows][64 k] bf16, 16B slot s stored at position s^(r&7)).
// A (1 MB) is L2-resident, read straight to registers. B (U/V) triple-buffered
// in LDS with prefetch distance 2 and COUNTED vmcnt(4) + raw s_barrier (never
// vmcnt(0) in the main loop) so each tile's DMAs get a full K-step (~1900 cyc)
// in flight — gemm5's double-buffer drained at every __syncthreads and only
// hid ~1/3 of HBM latency.

// Ae (sel=0) / Ao (sel=1): half-matrix [512 m'][512 j], blocked+swizzled.
__global__ void gen_dct_fold(__bf16* __restrict__ A) {
  int idx = blockIdx.x * blockDim.x + threadIdx.x;  // 0..65535
  int sel = idx >> 15;
  int rem = idx & 32767;
  int mp = rem >> 6;    // m' 0..511 (row within half-matrix)
  int slot = rem & 63;  // 16B slot within 512-wide j row
  int kt = slot >> 3, s = slot & 7;
  int k = 2 * mp + sel;  // actual DCT row
  int r = mp & 127, mtp = mp >> 7;
  float sc = (k == 0) ? 0.03125f : 0.04419417382415922f;
  int jb = kt * 64 + s * 8;
  bf16_8 v;
#pragma unroll
  for (int q = 0; q < 8; q++) {
    int j = jb + q;
    int t = (k * (2 * j + 1)) & 4095;               // exact phase mod 2*pi
    float ang = (float)t * 1.5339807878856412e-3f;  // pi/2048
    v[q] = (__bf16)(sc * cosf(ang));
  }
  *(bf16_8*)(A + (((size_t)(sel * 32 + mtp * 8 + kt)) << 13) + r * 64 +
             ((s ^ (r & 7)) << 3)) = v;
}

// x[b][j][n] f32 -> folded U/V blocked bf16 images.
// Image (b, sel, nt, kt) = [n=128 rows][j'=64] swizzled, at
//   B + ((b*2+sel)*64 + nt*8 + kt) * 8192.
#define TFP 132  // padded bf16 row stride: spreads transpose-read banks, keeps 8B align
__global__ __launch_bounds__(256) void fold_cvt(const float* __restrict__ x,
                                                __bf16* __restrict__ B) {
  __shared__ __bf16 Tu[64 * TFP];  // [j_local][n] bf16
  __shared__ __bf16 Tv[64 * TFP];
  const int t = threadIdx.x;
  const int kt = blockIdx.x, nt = blockIdx.y, b = blockIdx.z;
  const float* xb = x + (size_t)b * (NDIM * NDIM) + nt * 128;
  const int kr = t >> 5;        // 0..7
  const int c4 = (t & 31) * 4;  // float col (16B chunk)
  const int jb = kt * 64;         // top rows j = jb + k
  const int mb = 1023 - kt * 64;  // mirror rows = mb - k
#pragma unroll
  for (int u = 0; u < 8; u++) {
    int k = u * 8 + kr;
    f32x4 a = *(const f32x4*)(xb + (size_t)(jb + k) * NDIM + c4);
    f32x4 m = *(const f32x4*)(xb + (size_t)(mb - k) * NDIM + c4);
    f32x4 su = a + m, dv = a - m;
    bf16_4 wu, wv;
#pragma unroll
    for (int i = 0; i < 4; i++) {
      wu[i] = (__bf16)su[i];
      wv[i] = (__bf16)dv[i];
    }
    *(bf16_4*)(&Tu[k * TFP + c4]) = wu;  // banks: 2-way -> free
    *(bf16_4*)(&Tv[k * TFP + c4]) = wv;
  }
  __syncthreads();
  __bf16* outU = B + (((size_t)(b * 2 + 0) * 64 + nt * 8 + kt) << 13);
  __bf16* outV = B + (((size_t)(b * 2 + 1) * 64 + nt * 8 + kt) << 13);
#pragma unroll
  for (int u = 0; u < 4; u++) {
    int c = t * 4 + u;  // 16B output chunk; thread owns 64 contiguous bytes
    int r = c >> 3, sp = c & 7;
    int s = sp ^ (r & 7);  // data slot stored at position sp
    bf16_8 vU, vV;
#pragma unroll
    for (int q = 0; q < 8; q++) {  // transpose read; TFP pad spreads banks
      vU[q] = Tu[(s * 8 + q) * TFP + r];
      vV[q] = Tv[(s * 8 + q) * TFP + r];
    }
    *(bf16_8*)(outU + c * 8) = vU;
    *(bf16_8*)(outV + c * 8) = vV;
  }
}

// 128x128 tile, K=512 (8 steps of BK=64). B triple-buffered (48 KB), prefetch
// distance 2, counted vmcnt; A fragments to registers from L2, issued before
// the DMAs each step (A-loads oldest in queue -> their wait never drains the
// in-flight prefetch; explicit vmcnt(4) keeps the newest 4 DMAs in flight
// across the barrier).
__global__ __launch_bounds__(256, 3) void dct_gemm6(
    const __bf16* __restrict__ A, const __bf16* __restrict__ B,
    float* __restrict__ out) {
  __shared__ __align__(1024) __bf16 Bs[3][128 * 64];  // 3 x 16 KB
  const int t = threadIdx.x;
  const int w = t >> 6, lane = t & 63;
  const int nt = blockIdx.x, b = blockIdx.z;
  const int sel = blockIdx.y & 1, mtp = blockIdx.y >> 1;

  const __bf16* bg =
      B + (((size_t)(b * 2 + sel) * 64 + nt * 8) << 13) + w * 2048 + lane * 8;

  const int r16 = lane & 15;
  const int g8 = (lane >> 4) << 3;
  const int wm = (w & 1) << 6, wn = (w >> 1) << 6;
  const int xr = (r16 & 7) << 3;    // swizzle term (element units)
  const int kof0 = g8 ^ xr;         // k-half 0
  const int kof1 = (32 + g8) ^ xr;  // k-half 1

  // A fragment base: row (wm + i*16 + r16) of image (sel*32 + mtp*8 + kt)
  const __bf16* agf =
      A + (((size_t)(sel * 32 + mtp * 8)) << 13) + (size_t)(wm + r16) * 64;

  // prologue: stage tiles 0 and 1; wait only for tile 0 (vmcnt(4))
#pragma unroll
  for (int i = 0; i < 4; i++)
    async_copy16(bg + i * 512, &Bs[0][w * 2048 + i * 512]);
#pragma unroll
  for (int i = 0; i < 4; i++)
    async_copy16(bg + 8192 + i * 512, &Bs[1][w * 2048 + i * 512]);
  asm volatile("s_waitcnt vmcnt(4)" ::: "memory");
  __builtin_amdgcn_s_barrier();

  f32x4 acc[4][4] = {};

#pragma unroll
  for (int kt = 0; kt < 8; kt++) {
    const __bf16* as = agf + (size_t)kt * 8192;

    // (1) A-fragment loads FIRST (oldest in vmcnt queue)
    bf16_8 a0[4], a1[4];
#pragma unroll
    for (int i = 0; i < 4; i++) {
      a0[i] = *(const bf16_8*)(as + i * 1024 + kof0);
      a1[i] = *(const bf16_8*)(as + i * 1024 + kof1);
    }
    __builtin_amdgcn_sched_barrier(0);

    // (2) prefetch tile kt+2 (newest 4 vmem ops; stay in flight past barrier)
    if (kt < 6) {
      const __bf16* bn = bg + (size_t)(kt + 2) * 8192;
      __bf16* dst = &Bs[(kt + 2) % 3][w * 2048];
#pragma unroll
      for (int i = 0; i < 4; i++) async_copy16(bn + i * 512, dst + i * 512);
    }
    __builtin_amdgcn_sched_barrier(0);

    // (3) compute from Bs[kt%3]; compiler's A-wait retires tile kt+1's DMAs
    // (in flight a full step) but NOT this step's kt+2 DMAs.
    const __bf16* bs = &Bs[kt % 3][0];
#pragma unroll
    for (int h = 0; h < 2; h++) {
      const int kof = h ? kof1 : kof0;
      bf16_8 bfr[4];
#pragma unroll
      for (int j = 0; j < 4; j++)
        bfr[j] = *(const bf16_8*)(bs + (wn + j * 16 + r16) * 64 + kof);
#pragma unroll
      for (int i = 0; i < 4; i++)
#pragma unroll
        for (int j = 0; j < 4; j++)
          acc[i][j] = __builtin_amdgcn_mfma_f32_16x16x32_bf16(
              h ? a1[i] : a0[i], bfr[j], acc[i][j], 0, 0, 0);
    }

    // (4) counted-vmcnt barrier: tile kt+1 resident (all DMAs older than the
    // newest 4 retired); no ds_writes exist, own ds_reads retired by MFMA
    // data deps -> raw s_barrier is sufficient.
    asm volatile("s_waitcnt vmcnt(4)" ::: "memory");
    __builtin_amdgcn_s_barrier();
  }

  // epilogue: C/D layout col = lane&15, row_half = (lane>>4)*4 + reg;
  // physical out row = 2*row_half_global + sel (even/odd interleave).
  float* ob = out + (size_t)b * (NDIM * NDIM);
  const int rbase = (lane >> 4) << 2;
  const int cofs = lane & 15;
  const int n0 = nt * 128;
#pragma unroll
  for (int i = 0; i < 4; i++)
#pragma unroll
    for (int rr = 0; rr < 4; rr++) {
      int rh = mtp * 128 + wm + i * 16 + rbase + rr;
      int row = rh * 2 + sel;
#pragma unroll
      for (int j = 0; j < 4; j++) {
        int col = n0 + wn + j * 16 + cofs;
        ob[(size_t)row * NDIM + col] = acc[i][j][rr];
      }
    }
}

// ======================= FALLBACK PATH (small workspace) =======================
#define BM 128
#define BN 128
#define BK 32
#define BSTRIDE 40

__global__ void gen_dct_mat(__bf16* __restrict__ C) {
  int idx = blockIdx.x * blockDim.x + threadIdx.x;
  int k = idx >> 10;
  int j = idx & 1023;
  int t = (k * (2 * j + 1)) & 4095;
  float ang = (float)t * 1.5339807878856412e-3f;
  float s = (k == 0) ? 0.03125f : 0.04419417382415922f;
  C[idx] = (__bf16)(s * cosf(ang));
}

__global__ __launch_bounds__(256) void dct_gemm(
    const float* __restrict__ x, const __bf16* __restrict__ A,
    float* __restrict__ out) {
  __shared__ __align__(64) __bf16 Asm[BM * BK];
  __shared__ __align__(64) __bf16 Bsm[BN * BSTRIDE];

  const int t = threadIdx.x;
  const int wave = t >> 6;
  const int lane = t & 63;
  const int bb = blockIdx.z;
  const int m0 = blockIdx.y * BM;
  const int n0 = blockIdx.x * BN;

  const __bf16* Ag0 =
      A + (size_t)(m0 + wave * 16 + (lane >> 2)) * NDIM + ((lane & 3) * 8);
  const __bf16* Ag1 = Ag0 + (size_t)64 * NDIM;
  __bf16* Al0 = Asm + (wave * 16) * BK;
  __bf16* Al1 = Asm + (64 + wave * 16) * BK;

  const int bc = t & 127;
  const int bjg = t >> 7;
  const float* xs =
      x + (size_t)bb * (NDIM * NDIM) + (size_t)(bjg * 16) * NDIM + (n0 + bc);
  bf16_8* bs0 = (bf16_8*)(Bsm + bc * BSTRIDE + bjg * 16);
  bf16_8* bs1 = (bf16_8*)(Bsm + bc * BSTRIDE + bjg * 16 + 8);

  const int row16 = lane & 15;
  const int kq8 = (lane >> 4) * 8;
  const int wm = (wave & 1) * 64;
  const int wn = (wave >> 1) * 64;

  f32x4 acc[4][4] = {};

  for (int k0 = 0; k0 < NDIM; k0 += BK) {
    __syncthreads();
    async_copy16(Ag0 + k0, Al0);
    async_copy16(Ag1 + k0, Al1);

    const float* xp = xs + (size_t)k0 * NDIM;
    bf16_8 v0, v1;
#pragma unroll
    for (int q = 0; q < 8; q++) {
      v0[q] = (__bf16)xp[(size_t)q * NDIM];
      v1[q] = (__bf16)xp[(size_t)(q + 8) * NDIM];
    }
    *bs0 = v0;
    *bs1 = v1;
    __syncthreads();

    bf16_8 af[4], bfr[4];
#pragma unroll
    for (int i = 0; i < 4; i++)
      af[i] = *(const bf16_8*)(Asm + (wm + i * 16 + row16) * BK + kq8);
#pragma unroll
    for (int j = 0; j < 4; j++)
      bfr[j] = *(const bf16_8*)(Bsm + (wn + j * 16 + row16) * BSTRIDE + kq8);
#pragma unroll
    for (int i = 0; i < 4; i++)
#pragma unroll
      for (int j = 0; j < 4; j++)
        acc[i][j] = __builtin_amdgcn_mfma_f32_16x16x32_bf16(af[i], bfr[j],
                                                            acc[i][j], 0, 0, 0);
  }

  float* ob = out + (size_t)bb * (NDIM * NDIM);
  const int rbase = (lane >> 4) * 4;
  const int cofs = lane & 15;
#pragma unroll
  for (int i = 0; i < 4; i++) {
#pragma unroll
    for (int r = 0; r < 4; r++) {
      int row = m0 + wm + i * 16 + rbase + r;
#pragma unroll
      for (int j = 0; j < 4; j++) {
        int col = n0 + wn + j * 16 + cofs;
        ob[(size_t)row * NDIM + col] = acc[i][j][r];
      }
    }
  }
}

extern "C" void kernel_launch(void* const* d_in, const int* in_sizes, int n_in,
                              void* d_out, int out_size, void* d_ws,
                              size_t ws_size, hipStream_t stream) {
  const float* x = (const float*)d_in[0];
  float* out = (float*)d_out;

  const size_t need = (size_t)66 * 1024 * 1024;  // 2 MB A + 64 MB folded U/V
  if (ws_size >= need) {
    __bf16* Ab = (__bf16*)d_ws;                       // 2*512*512 bf16 = 1 MB
    __bf16* Bb = (__bf16*)((char*)d_ws + (size_t)2 * 1024 * 1024);  // 64 MB
    gen_dct_fold<<<dim3(256), dim3(256), 0, stream>>>(Ab);
    fold_cvt<<<dim3(8, 8, 32), dim3(256), 0, stream>>>(x, Bb);
    dct_gemm6<<<dim3(8, 8, 32), dim3(256), 0, stream>>>(Ab, Bb, out);
  } else {
    __bf16* Cmat = (__bf16*)d_ws;  // 2 MB
    gen_dct_mat<<<dim3((NDIM * NDIM) / 256), dim3(256), 0, stream>>>(Cmat);
    dct_gemm<<<dim3(NDIM / BN, NDIM / BM, 32), dim3(256), 0, stream>>>(x, Cmat,
                                                                       out);
  }
}